// Round 11
// baseline (361.745 us; speedup 1.0000x reference)
//
#include <hip/hip_runtime.h>
#include <hip/hip_bf16.h>
#include <math.h>
#include <stdint.h>

#define NN 2048
#define DD 512
#define EE 65536
#define EPSV 0.5f
#define SEN 2048   // covered-rank sentinel (= n in the reference)
#define PADE 98304 // padded edge capacity per direction
#define NPART 4    // partial-histogram blocks (kills the ws memset)

static const size_t SZ = (size_t)NN * NN;  // 4,194,304

// ---------------------------------------------------------------------------
// Degree counting via per-block LDS histograms -> PARTIAL global arrays
// (fully written: no memset needed). R8 verbatim.
// ---------------------------------------------------------------------------
__global__ __launch_bounds__(1024) void count_deg8(const int* __restrict__ row,
                                                   const int* __restrict__ col,
                                                   int* __restrict__ pdeg,
                                                   int* __restrict__ pcdeg) {
  __shared__ int ld[NN], lc[NN];
  int t = threadIdx.x, b = blockIdx.x;
  for (int v = t; v < NN; v += 1024) { ld[v] = 0; lc[v] = 0; }
  __syncthreads();
  int base = b * (EE / NPART);
  for (int e = t; e < EE / NPART; e += 1024) {
    atomicAdd(&ld[row[base + e]], 1);
    atomicAdd(&lc[col[base + e]], 1);
  }
  __syncthreads();
  for (int v = t; v < NN; v += 1024) {
    pdeg[b * NN + v] = ld[v];
    pcdeg[b * NN + v] = lc[v];
  }
}

// ---------------------------------------------------------------------------
// Dual CSR/CSC scan + self-edge padding (R8 verbatim). Zeroes counts.
// ---------------------------------------------------------------------------
__global__ __launch_bounds__(1024) void csr_scan_pad(const int* __restrict__ pdeg,
                                                     const int* __restrict__ pcdeg,
                                                     int* __restrict__ row_ptr,
                                                     int* __restrict__ fill_ptr,
                                                     int* __restrict__ col_ptr,
                                                     int* __restrict__ cfill_ptr,
                                                     unsigned short* __restrict__ colidx,
                                                     unsigned short* __restrict__ rowidx,
                                                     float* __restrict__ avals,
                                                     int* __restrict__ counts) {
  __shared__ int a[NN], b[NN], c[NN], d[NN];
  __shared__ int dg_s[NN], cg_s[NN];
  int t = threadIdx.x;
  for (int v = t; v < NN; v += 1024) {
    int dg = pdeg[v] + pdeg[NN + v] + pdeg[2 * NN + v] + pdeg[3 * NN + v];
    int cg = pcdeg[v] + pcdeg[NN + v] + pcdeg[2 * NN + v] + pcdeg[3 * NN + v];
    dg_s[v] = dg;
    cg_s[v] = cg;
    a[v] = (dg + 15) & ~15;
    c[v] = (cg + 15) & ~15;
    counts[v] = 0;
  }
  __syncthreads();
  int* s1 = a; int* d1 = b; int* s2 = c; int* d2 = d;
  for (int off = 1; off < NN; off <<= 1) {
    for (int v = t; v < NN; v += 1024) {
      d1[v] = s1[v] + (v >= off ? s1[v - off] : 0);
      d2[v] = s2[v] + (v >= off ? s2[v - off] : 0);
    }
    __syncthreads();
    int* tp = s1; s1 = d1; d1 = tp;
    tp = s2; s2 = d2; d2 = tp;
  }
  for (int v = t; v < NN; v += 1024) {
    int dg = dg_s[v];
    int end = s1[v];
    int excl = end - ((dg + 15) & ~15);
    row_ptr[v] = excl;
    fill_ptr[v] = excl;
    for (int e = excl + dg; e < end; ++e) {  // CSR self pad, zero weight
      colidx[e] = (unsigned short)v;
      avals[e] = 0.f;
    }
    dg = cg_s[v];
    end = s2[v];
    excl = end - ((dg + 15) & ~15);
    col_ptr[v] = excl;
    cfill_ptr[v] = excl;
    for (int e = excl + dg; e < end; ++e) rowidx[e] = (unsigned short)v;  // CSC self pad
  }
  if (t == 0) {
    row_ptr[NN] = s1[NN - 1];
    col_ptr[NN] = s2[NN - 1];
  }
}

// Multi-block scatter fill: full-chip memory parallelism (R8 verbatim).
__global__ __launch_bounds__(256) void csr_fill(const int* __restrict__ row,
                                                const int* __restrict__ col,
                                                const float* __restrict__ attr,
                                                int* __restrict__ fill_ptr,
                                                int* __restrict__ cfill_ptr,
                                                unsigned short* __restrict__ colidx,
                                                unsigned short* __restrict__ rowidx,
                                                float* __restrict__ avals) {
  int e = blockIdx.x * 256 + threadIdx.x;
  int r = row[e], c = col[e];
  int pos = atomicAdd(&fill_ptr[r], 1);
  colidx[pos] = (unsigned short)c;
  avals[pos] = attr[e];
  rowidx[atomicAdd(&cfill_ptr[c], 1)] = (unsigned short)r;
}

// ---------------------------------------------------------------------------
// FUSED (R8 verbatim, PASSED at 233.0): block 0 = greedy maximal
// k-independent set (k=2) worklist; blocks 1..NN = rw row build (into
// out_pinv region) + zero slices of adj_c and x_pool under the MIS shadow.
// ---------------------------------------------------------------------------
__global__ __launch_bounds__(1024) void fused_mis_rw(const int* __restrict__ row_ptr_g,
                                                     const int* __restrict__ col_ptr_g,
                                                     const unsigned short* __restrict__ colidx,
                                                     const unsigned short* __restrict__ rowidx,
                                                     const int* __restrict__ rank_g,
                                                     int* __restrict__ mis_flag,
                                                     int* __restrict__ mis_list,
                                                     int* __restrict__ mis_count,
                                                     const float* __restrict__ avals,
                                                     float* __restrict__ rw,
                                                     float* __restrict__ adjc,
                                                     float* __restrict__ xp) {
  if (blockIdx.x == 0) {
    // ---------------- MIS role (verbatim) ----------------
    __shared__ int rank_s[NN];
    __shared__ int mr[NN];
    __shared__ int cov[NN];
    __shared__ int dly[NN];
    __shared__ int mis_s[NN];
    __shared__ int row_ptr_s[NN + 1];
    __shared__ int col_ptr_s[NN + 1];
    __shared__ int unc[2][NN];
    __shared__ int dl[NN];
    __shared__ int ucnt[2];
    __shared__ int dcnt;
    __shared__ int cnt;
    int t = threadIdx.x;
    const uint4* col4 = (const uint4*)colidx;  // 8 u16 per uint4
    const uint4* row4 = (const uint4*)rowidx;

    for (int v = t; v < NN; v += 1024) {
      int rk = rank_g[v];
      rank_s[v] = rk;
      mr[v] = rk;
      cov[v] = 0;
      dly[v] = 0;
      mis_s[v] = 0;
      row_ptr_s[v] = row_ptr_g[v];
      col_ptr_s[v] = col_ptr_g[v];
      unc[0][v] = v;
    }
    if (t == 0) {
      row_ptr_s[NN] = row_ptr_g[NN];
      col_ptr_s[NN] = col_ptr_g[NN];
      ucnt[0] = NN;
      ucnt[1] = 0;
      dcnt = 0;
      cnt = 0;
    }
    __syncthreads();

    int cur = 0;
    for (int round = 0; round < NN; ++round) {
      int U = ucnt[cur];
      if (round) {  // R0: batched reset
        for (int v = t; v < NN; v += 1024) {
          mr[v] = cov[v] ? SEN : rank_s[v];
          dly[v] = 0;
        }
        if (t == 0) { ucnt[cur ^ 1] = 0; dcnt = 0; }
        __syncthreads();
      }
      // A: min hop0 scatter from uncovered sources
      for (int i = t; i < U; i += 1024) {
        int v = unc[cur][i];
        int val = rank_s[v];
        int e0 = row_ptr_s[v];
        int nch = (row_ptr_s[v + 1] - e0) >> 3;
        const uint4* b4 = col4 + (e0 >> 3);
        for (int cI = 0; cI < nch; cI += 2) {
          uint4 A = b4[cI], B = b4[cI + 1];
          atomicMin(&mr[A.x & 0xFFFFu], val); atomicMin(&mr[A.x >> 16], val);
          atomicMin(&mr[A.y & 0xFFFFu], val); atomicMin(&mr[A.y >> 16], val);
          atomicMin(&mr[A.z & 0xFFFFu], val); atomicMin(&mr[A.z >> 16], val);
          atomicMin(&mr[A.w & 0xFFFFu], val); atomicMin(&mr[A.w >> 16], val);
          atomicMin(&mr[B.x & 0xFFFFu], val); atomicMin(&mr[B.x >> 16], val);
          atomicMin(&mr[B.y & 0xFFFFu], val); atomicMin(&mr[B.y >> 16], val);
          atomicMin(&mr[B.z & 0xFFFFu], val); atomicMin(&mr[B.z >> 16], val);
          atomicMin(&mr[B.w & 0xFFFFu], val); atomicMin(&mr[B.w >> 16], val);
        }
      }
      __syncthreads();
      // CD: min hop1 gather (CSC) + delta detect + dl append
      for (int i = t; i < U; i += 1024) {
        int v = unc[cur][i];
        int val = mr[v];
        int e0 = col_ptr_s[v];
        int nch = (col_ptr_s[v + 1] - e0) >> 3;
        const uint4* b4 = row4 + (e0 >> 3);
        for (int cI = 0; cI < nch; cI += 2) {
          uint4 A = b4[cI], B = b4[cI + 1];
          int m0 = min(mr[A.x & 0xFFFFu], mr[A.x >> 16]);
          int m1 = min(mr[A.y & 0xFFFFu], mr[A.y >> 16]);
          int m2 = min(mr[A.z & 0xFFFFu], mr[A.z >> 16]);
          int m3 = min(mr[A.w & 0xFFFFu], mr[A.w >> 16]);
          int m4 = min(mr[B.x & 0xFFFFu], mr[B.x >> 16]);
          int m5 = min(mr[B.y & 0xFFFFu], mr[B.y >> 16]);
          int m6 = min(mr[B.z & 0xFFFFu], mr[B.z >> 16]);
          int m7 = min(mr[B.w & 0xFFFFu], mr[B.w >> 16]);
          val = min(val, min(min(min(m0, m1), min(m2, m3)),
                             min(min(m4, m5), min(m6, m7))));
        }
        if (rank_s[v] == val) {
          mis_s[v] = 1;
          dly[v] = 1;  // keep-self of OR hop0
          dl[atomicAdd(&dcnt, 1)] = v;  // unordered (consumers order-free)
        }
      }
      __syncthreads();
      // E: OR hop0 scatter from delta
      int D = dcnt;
      for (int i = t; i < D; i += 1024) {
        int v = dl[i];
        int e0 = row_ptr_s[v];
        int nch = (row_ptr_s[v + 1] - e0) >> 3;
        const uint4* b4 = col4 + (e0 >> 3);
        for (int cI = 0; cI < nch; cI += 2) {
          uint4 A = b4[cI], B = b4[cI + 1];
          dly[A.x & 0xFFFFu] = 1; dly[A.x >> 16] = 1;
          dly[A.y & 0xFFFFu] = 1; dly[A.y >> 16] = 1;
          dly[A.z & 0xFFFFu] = 1; dly[A.z >> 16] = 1;
          dly[A.w & 0xFFFFu] = 1; dly[A.w >> 16] = 1;
          dly[B.x & 0xFFFFu] = 1; dly[B.x >> 16] = 1;
          dly[B.y & 0xFFFFu] = 1; dly[B.y >> 16] = 1;
          dly[B.z & 0xFFFFu] = 1; dly[B.z >> 16] = 1;
          dly[B.w & 0xFFFFu] = 1; dly[B.w >> 16] = 1;
        }
      }
      __syncthreads();
      // GH: OR hop1 gather (CSC) + fold + survivor-list rebuild
      for (int i = t; i < U; i += 1024) {
        int v = unc[cur][i];
        int c1 = dly[v];
        if (!c1) {
          int e0 = col_ptr_s[v];
          int nch = (col_ptr_s[v + 1] - e0) >> 3;
          const uint4* b4 = row4 + (e0 >> 3);
          for (int cI = 0; cI < nch; cI += 2) {
            uint4 A = b4[cI], B = b4[cI + 1];
            c1 |= dly[A.x & 0xFFFFu] | dly[A.x >> 16] |
                  dly[A.y & 0xFFFFu] | dly[A.y >> 16] |
                  dly[A.z & 0xFFFFu] | dly[A.z >> 16] |
                  dly[A.w & 0xFFFFu] | dly[A.w >> 16] |
                  dly[B.x & 0xFFFFu] | dly[B.x >> 16] |
                  dly[B.y & 0xFFFFu] | dly[B.y >> 16] |
                  dly[B.z & 0xFFFFu] | dly[B.z >> 16] |
                  dly[B.w & 0xFFFFu] | dly[B.w >> 16];
            if (c1) break;
          }
        }
        if (c1) cov[v] = 1;
        else unc[cur ^ 1][atomicAdd(&ucnt[cur ^ 1], 1)] = v;
      }
      __syncthreads();
      if (ucnt[cur ^ 1] == 0) break;
      cur ^= 1;
    }

    for (int v = t; v < NN; v += 1024) {
      int s = mis_s[v];
      mis_flag[v] = s;
      if (s) mis_list[atomicAdd(&cnt, 1)] = v;
    }
    __syncthreads();
    if (t == 0) *mis_count = cnt;
  } else {
    // ---------------- rw row build + output-zero role (verbatim) ----------
    __shared__ float rowbuf[NN];
    __shared__ float ssum;
    int i = blockIdx.x - 1;
    int t = threadIdx.x;
    // zero adj_c slice (8KB/block) and x_pool slice (2KB/block) in the shadow
    float4 z4 = make_float4(0.f, 0.f, 0.f, 0.f);
    if (t < 512) ((float4*)(adjc + (size_t)i * NN))[t] = z4;
    if (t < 128) ((float4*)xp)[(size_t)i * 128 + t] = z4;
    for (int j = t; j < NN; j += 1024) rowbuf[j] = 0.f;
    if (t == 0) ssum = 0.f;
    __syncthreads();
    int e0 = row_ptr_g[i], e1 = row_ptr_g[i + 1];
    float part = 0.f;
    for (int e = e0 + t; e < e1; e += 1024) {  // deg < 256 => same edge->thread map
      float a = avals[e];
      atomicAdd(&rowbuf[colidx[e]], a);
      part += a;
    }
    for (int off = 32; off; off >>= 1) part += __shfl_down(part, off);
    if ((t & 63) == 0) atomicAdd(&ssum, part);
    __syncthreads();
    float s = ssum;
    s = (s > 0.f) ? s : 1.f;
    for (int j = t; j < NN; j += 1024) {
      float v = rowbuf[j] / s;
      v = (i == j) ? (v + EPSV) : (v * (1.f - EPSV));
      rw[(size_t)i * NN + j] = v;
    }
  }
}

// ---------------------------------------------------------------------------
// Bc compact-row gather from rw columns — ONCE, globally (verified).
// ---------------------------------------------------------------------------
__global__ __launch_bounds__(256) void bc_gather(const float* __restrict__ rw,
                                                 const int* __restrict__ mis_list,
                                                 const int* __restrict__ mis_count,
                                                 float* __restrict__ Bc) {
  int M = *mis_count;
  int total = M * NN;
  int stride = gridDim.x * 256;
  for (int j = blockIdx.x * 256 + threadIdx.x; j < total; j += stride) {
    int tc = j >> 11, i = j & (NN - 1);
    Bc[(size_t)tc * NN + i] = rw[(size_t)i * NN + mis_list[tc]];
  }
}

// ---------------------------------------------------------------------------
// c2 + Gumbel-argmax + DIRECT decode/counts (R8 verbatim, PASSED).
// ---------------------------------------------------------------------------
__device__ inline unsigned int f32_key(float x) {
  unsigned int u = __float_as_uint(x);
  return (u & 0x80000000u) ? ~u : (u | 0x80000000u);
}
__device__ inline float dot4(float4 a, float4 b) {
  return ((a.x * b.x + a.y * b.y) + (a.z * b.z + a.w * b.w));
}
__device__ inline unsigned long long umax64(unsigned long long a, unsigned long long b) {
  return a > b ? a : b;
}
__device__ inline int pdecode(unsigned long long p) {
  return (p == 0ull) ? 0 : (NN - 1 - (int)(p & 0xFFFFFFFFull));
}

__global__ __launch_bounds__(256) void c2_all(const float* __restrict__ rw,
                                              const float* __restrict__ Bc,
                                              const float* __restrict__ u,
                                              const int* __restrict__ mis_list,
                                              const int* __restrict__ mis_count,
                                              int* __restrict__ cluster,
                                              int* __restrict__ counts) {
  int M = *mis_count;
  int lane = threadIdx.x & 63, w = threadIdx.x >> 6;
  int r0 = blockIdx.x * 8 + w * 2;  // 256 blocks x 4 warps x 2 rows = 2048
  const float4* rp0 = (const float4*)(rw + (size_t)r0 * NN);
  const float4* rp1 = (const float4*)(rw + (size_t)(r0 + 1) * NN);
  float4 A0[8], A1[8];
#pragma unroll
  for (int q = 0; q < 8; ++q) {
    A0[q] = rp0[q * 64 + lane];
    A1[q] = rp1[q * 64 + lane];
  }
  unsigned long long best0 = 0ull, best1 = 0ull;
  for (int j = 0; j < M; ++j) {
    int m = mis_list[j];
    const float4* cb = (const float4*)(Bc + (size_t)j * NN);
    float4 B[8];
#pragma unroll
    for (int q = 0; q < 8; ++q) B[q] = cb[q * 64 + lane];
    // row 0 — identical tree + shuffle order as the verified kernel
    float s01 = dot4(A0[0], B[0]) + dot4(A0[1], B[1]);
    float s23 = dot4(A0[2], B[2]) + dot4(A0[3], B[3]);
    float s45 = dot4(A0[4], B[4]) + dot4(A0[5], B[5]);
    float s67 = dot4(A0[6], B[6]) + dot4(A0[7], B[7]);
    float s = (s01 + s23) + (s45 + s67);
    s += __shfl_xor(s, 32);
    s += __shfl_xor(s, 16);
    s += __shfl_xor(s, 8);
    s += __shfl_xor(s, 4);
    s += __shfl_xor(s, 2);
    s += __shfl_xor(s, 1);
    // row 1
    float t01 = dot4(A1[0], B[0]) + dot4(A1[1], B[1]);
    float t23 = dot4(A1[2], B[2]) + dot4(A1[3], B[3]);
    float t45 = dot4(A1[4], B[4]) + dot4(A1[5], B[5]);
    float t67 = dot4(A1[6], B[6]) + dot4(A1[7], B[7]);
    float tt = (t01 + t23) + (t45 + t67);
    tt += __shfl_xor(tt, 32);
    tt += __shfl_xor(tt, 16);
    tt += __shfl_xor(tt, 8);
    tt += __shfl_xor(tt, 4);
    tt += __shfl_xor(tt, 2);
    tt += __shfl_xor(tt, 1);
    if (lane == 0) {
      if (s > 0.f) {
        float uu = u[(size_t)r0 * NN + m];
        float g = -logf(-logf(uu + 1e-20f) + 1e-20f);
        float logit = logf(s) + g;
        best0 = umax64(best0, ((unsigned long long)f32_key(logit) << 32) |
                                  (unsigned int)(NN - 1 - m));
      }
      if (tt > 0.f) {
        float uu = u[(size_t)(r0 + 1) * NN + m];
        float g = -logf(-logf(uu + 1e-20f) + 1e-20f);
        float logit = logf(tt) + g;
        best1 = umax64(best1, ((unsigned long long)f32_key(logit) << 32) |
                                  (unsigned int)(NN - 1 - m));
      }
    }
  }
  if (lane == 0) {
    int m0b = pdecode(best0);
    cluster[r0] = m0b;
    atomicAdd(&counts[m0b], 1);
    int m1b = pdecode(best1);
    cluster[r0 + 1] = m1b;
    atomicAdd(&counts[m1b], 1);
  }
}

// ---------------------------------------------------------------------------
// Final fused pass: c_hard + p_inv + mis writes, adj_c edge scatter, and
// x_pool via OWNERSHIP GATHER (replaces the 1M-atomicAdd scatter onto only
// M*512 ~ 20K addresses == ~50-way f32 atomic contention — Guideline-12
// violation). Blocks 0..2*NN own (cluster-row r = b>>1, 256-dim chunk);
// rows with counts[r]==0 exit after ONE read (xp pre-zeroed in fused).
// Working blocks (~2M) stage cluster[] in LDS, accumulate raw x, scale by
// 1/cnt once — deterministic, race-free, same sum as reference (which also
// does sum-then-scale).
// ---------------------------------------------------------------------------
__global__ __launch_bounds__(256) void scatter_chpm(const int* __restrict__ row,
                                                    const int* __restrict__ col,
                                                    const float* __restrict__ attr,
                                                    const float* __restrict__ x,
                                                    const int* __restrict__ cluster,
                                                    const int* __restrict__ counts,
                                                    const int* __restrict__ mis_flag,
                                                    float* __restrict__ out_ch,
                                                    float* __restrict__ out_pinv,
                                                    float* __restrict__ out_mis,
                                                    float* __restrict__ adjc,
                                                    float* __restrict__ xp) {
  __shared__ int clus_s[NN];
  int t = threadIdx.x;
  int idx = blockIdx.x * 256 + t;  // over N*N
  int a = idx >> 11, b = idx & (NN - 1);
  out_ch[idx] = (cluster[a] == b) ? 1.f : 0.f;
  float pv = 0.f;
  if (cluster[b] == a) {
    int c = counts[a];
    pv = 1.f / (float)(c > 0 ? c : 1);
  }
  out_pinv[idx] = pv;
  if (idx < NN) out_mis[idx] = mis_flag[idx] ? 1.f : 0.f;
  // x_pool ownership gather: blocks [0, 2*NN) own (r, dim-chunk)
  if (blockIdx.x < 2 * NN) {
    int r = blockIdx.x >> 1;
    int cnt = counts[r];
    if (cnt > 0) {  // only ~M*2 blocks proceed; rest exit after 1 read
      for (int v = t; v < NN; v += 256) clus_s[v] = cluster[v];
      __syncthreads();
      int d = (blockIdx.x & 1) * 256 + t;  // each (r,d) has ONE writer
      float acc = 0.f;
      for (int i = 0; i < NN; ++i) {
        if (clus_s[i] == r) acc += x[(size_t)i * DD + d];
      }
      xp[(size_t)r * DD + d] = acc / (float)cnt;
    }
  }
  if (idx < EE) {
    atomicAdd(&adjc[(size_t)cluster[row[idx]] * NN + cluster[col[idx]]], attr[idx]);
  }
}

// ---------------------------------------------------------------------------
extern "C" void kernel_launch(void* const* d_in, const int* in_sizes, int n_in,
                              void* d_out, int out_size, void* d_ws, size_t ws_size,
                              hipStream_t stream) {
  const int*   edge_index = (const int*)d_in[0];
  const float* edge_attr  = (const float*)d_in[1];
  const float* x          = (const float*)d_in[2];
  const int*   rank       = (const int*)d_in[3];
  const float* u          = (const float*)d_in[4];
  float* out              = (float*)d_out;  // f32 outputs, concatenated

  const int* row = edge_index;
  const int* col = edge_index + EE;

  float* out_adjc = out;                 // N*N — zeroed early (fused), adj_c scatter target
  float* out_ch   = out + SZ;            // N*N — doubles as Bc scratch
  float* out_pinv = out + 2 * SZ;        // N*N — doubles as rw scratch
  float* out_mis  = out + 3 * SZ;        // N
  float* out_xp   = out + 3 * SZ + NN;   // N*D

  // d_ws layout (~896 KB). NO memset: pdeg/pcdeg fully written by
  // count_deg8; counts zeroed inside csr_scan_pad; rest fully written
  // before read.
  int*   counts    = (int*)d_ws;                   // N
  int*   mis_flag  = counts + NN;                  // N
  int*   cluster   = mis_flag + NN;                // N
  int*   mis_list  = cluster + NN;                 // N
  int*   mis_count = mis_list + NN;                // 1
  int*   fill_ptr  = mis_count + 1;                // N
  int*   cfill_ptr = fill_ptr + NN;                // N
  int*   row_ptr   = cfill_ptr + NN;               // N+1
  int*   col_ptr   = row_ptr + NN + 1;             // N+1
  int*   pdeg      = col_ptr + NN + 1;             // NPART*N partial histograms
  int*   pcdeg     = pdeg + NPART * NN;            // NPART*N
  unsigned short* colidx =                          // PADE u16, 32B-aligned
      (unsigned short*)(((uintptr_t)(pcdeg + NPART * NN) + 31) & ~(uintptr_t)31);
  unsigned short* rowidx = colidx + PADE;          // PADE u16
  float* avals = (float*)(rowidx + PADE);          // PADE f32 (CSR edge weights)

  count_deg8<<<NPART, 1024, 0, stream>>>(row, col, pdeg, pcdeg);
  csr_scan_pad<<<1, 1024, 0, stream>>>(pdeg, pcdeg, row_ptr, fill_ptr, col_ptr,
                                       cfill_ptr, colidx, rowidx, avals, counts);
  csr_fill<<<EE / 256, 256, 0, stream>>>(row, col, edge_attr, fill_ptr, cfill_ptr,
                                         colidx, rowidx, avals);
  // block 0 = MIS (1 CU, ~47us); blocks 1..NN = rw rows + adjc/xp zeroing (hidden)
  fused_mis_rw<<<NN + 1, 1024, 0, stream>>>(row_ptr, col_ptr, colidx, rowidx, rank,
                                            mis_flag, mis_list, mis_count,
                                            avals, out_pinv /*rw*/, out_adjc, out_xp);
  bc_gather<<<256, 256, 0, stream>>>(out_pinv, mis_list, mis_count, out_ch);
  c2_all<<<NN / 8, 256, 0, stream>>>(out_pinv, out_ch, u, mis_list, mis_count,
                                     cluster, counts);
  scatter_chpm<<<(NN * NN) / 256, 256, 0, stream>>>(row, col, edge_attr, x, cluster,
                                                    counts, mis_flag, out_ch, out_pinv,
                                                    out_mis, out_adjc, out_xp);
}

// Round 12
// 225.431 us; speedup vs baseline: 1.6047x; 1.6047x over previous
//
#include <hip/hip_runtime.h>
#include <hip/hip_bf16.h>
#include <math.h>
#include <stdint.h>

#define NN 2048
#define DD 512
#define EE 65536
#define EPSV 0.5f
#define SEN 2048   // covered-rank sentinel (= n in the reference)
#define PADE 98304 // padded edge capacity per direction
#define NPART 4    // partial-histogram blocks (kills the ws memset)

static const size_t SZ = (size_t)NN * NN;  // 4,194,304

// ---------------------------------------------------------------------------
// Degree counting via per-block LDS histograms -> per-block PARTIAL global
// arrays (fully written, so no memset/zero-init of any kind is needed).
// 4 blocks x 1024 threads, 16 edges/thread, LDS atomics — full parallelism.
// ---------------------------------------------------------------------------
__global__ __launch_bounds__(1024) void count_deg8(const int* __restrict__ row,
                                                   const int* __restrict__ col,
                                                   int* __restrict__ pdeg,
                                                   int* __restrict__ pcdeg) {
  __shared__ int ld[NN], lc[NN];
  int t = threadIdx.x, b = blockIdx.x;
  for (int v = t; v < NN; v += 1024) { ld[v] = 0; lc[v] = 0; }
  __syncthreads();
  int base = b * (EE / NPART);
  for (int e = t; e < EE / NPART; e += 1024) {
    atomicAdd(&ld[row[base + e]], 1);
    atomicAdd(&lc[col[base + e]], 1);
  }
  __syncthreads();
  for (int v = t; v < NN; v += 1024) {
    pdeg[b * NN + v] = ld[v];
    pcdeg[b * NN + v] = lc[v];
  }
}

// ---------------------------------------------------------------------------
// Dual CSR/CSC scan + self-edge padding (interleaved Hillis-Steele, 1 block).
// Degrees come from summing the 4 partial histograms (kept in LDS for the
// pad phase). Pads: CSR gets self-edges with avals=0 (exact: +0 to
// adj/rowsum; prop_min keeps self; OR to self idempotent). Zeroes counts.
// ---------------------------------------------------------------------------
__global__ __launch_bounds__(1024) void csr_scan_pad(const int* __restrict__ pdeg,
                                                     const int* __restrict__ pcdeg,
                                                     int* __restrict__ row_ptr,
                                                     int* __restrict__ fill_ptr,
                                                     int* __restrict__ col_ptr,
                                                     int* __restrict__ cfill_ptr,
                                                     unsigned short* __restrict__ colidx,
                                                     unsigned short* __restrict__ rowidx,
                                                     float* __restrict__ avals,
                                                     int* __restrict__ counts) {
  __shared__ int a[NN], b[NN], c[NN], d[NN];
  __shared__ int dg_s[NN], cg_s[NN];
  int t = threadIdx.x;
  for (int v = t; v < NN; v += 1024) {
    int dg = pdeg[v] + pdeg[NN + v] + pdeg[2 * NN + v] + pdeg[3 * NN + v];
    int cg = pcdeg[v] + pcdeg[NN + v] + pcdeg[2 * NN + v] + pcdeg[3 * NN + v];
    dg_s[v] = dg;
    cg_s[v] = cg;
    a[v] = (dg + 15) & ~15;
    c[v] = (cg + 15) & ~15;
    counts[v] = 0;
  }
  __syncthreads();
  int* s1 = a; int* d1 = b; int* s2 = c; int* d2 = d;
  for (int off = 1; off < NN; off <<= 1) {
    for (int v = t; v < NN; v += 1024) {
      d1[v] = s1[v] + (v >= off ? s1[v - off] : 0);
      d2[v] = s2[v] + (v >= off ? s2[v - off] : 0);
    }
    __syncthreads();
    int* tp = s1; s1 = d1; d1 = tp;
    tp = s2; s2 = d2; d2 = tp;
  }
  for (int v = t; v < NN; v += 1024) {
    int dg = dg_s[v];
    int end = s1[v];
    int excl = end - ((dg + 15) & ~15);
    row_ptr[v] = excl;
    fill_ptr[v] = excl;
    for (int e = excl + dg; e < end; ++e) {  // CSR self pad, zero weight
      colidx[e] = (unsigned short)v;
      avals[e] = 0.f;
    }
    dg = cg_s[v];
    end = s2[v];
    excl = end - ((dg + 15) & ~15);
    col_ptr[v] = excl;
    cfill_ptr[v] = excl;
    for (int e = excl + dg; e < end; ++e) rowidx[e] = (unsigned short)v;  // CSC self pad
  }
  if (t == 0) {
    row_ptr[NN] = s1[NN - 1];
    col_ptr[NN] = s2[NN - 1];
  }
}

// Multi-block scatter fill: full-chip memory parallelism (R6 verbatim).
__global__ __launch_bounds__(256) void csr_fill(const int* __restrict__ row,
                                                const int* __restrict__ col,
                                                const float* __restrict__ attr,
                                                int* __restrict__ fill_ptr,
                                                int* __restrict__ cfill_ptr,
                                                unsigned short* __restrict__ colidx,
                                                unsigned short* __restrict__ rowidx,
                                                float* __restrict__ avals) {
  int e = blockIdx.x * 256 + threadIdx.x;
  int r = row[e], c = col[e];
  int pos = atomicAdd(&fill_ptr[r], 1);
  colidx[pos] = (unsigned short)c;
  avals[pos] = attr[e];
  rowidx[atomicAdd(&cfill_ptr[c], 1)] = (unsigned short)r;
}

// ---------------------------------------------------------------------------
// FUSED (R6 verbatim except the misinv write is dropped — mis_list order is
// consumed order-independently): block 0 = greedy maximal k-independent set
// (k=2) worklist; blocks 1..NN = rw row build (into out_pinv region) + zero
// slices of adj_c and x_pool, all hidden under the MIS shadow.
// ---------------------------------------------------------------------------
__global__ __launch_bounds__(1024) void fused_mis_rw(const int* __restrict__ row_ptr_g,
                                                     const int* __restrict__ col_ptr_g,
                                                     const unsigned short* __restrict__ colidx,
                                                     const unsigned short* __restrict__ rowidx,
                                                     const int* __restrict__ rank_g,
                                                     int* __restrict__ mis_flag,
                                                     int* __restrict__ mis_list,
                                                     int* __restrict__ mis_count,
                                                     const float* __restrict__ avals,
                                                     float* __restrict__ rw,
                                                     float* __restrict__ adjc,
                                                     float* __restrict__ xp) {
  if (blockIdx.x == 0) {
    // ---------------- MIS role (verbatim) ----------------
    __shared__ int rank_s[NN];
    __shared__ int mr[NN];
    __shared__ int cov[NN];
    __shared__ int dly[NN];
    __shared__ int mis_s[NN];
    __shared__ int row_ptr_s[NN + 1];
    __shared__ int col_ptr_s[NN + 1];
    __shared__ int unc[2][NN];
    __shared__ int dl[NN];
    __shared__ int ucnt[2];
    __shared__ int dcnt;
    __shared__ int cnt;
    int t = threadIdx.x;
    const uint4* col4 = (const uint4*)colidx;  // 8 u16 per uint4
    const uint4* row4 = (const uint4*)rowidx;

    for (int v = t; v < NN; v += 1024) {
      int rk = rank_g[v];
      rank_s[v] = rk;
      mr[v] = rk;
      cov[v] = 0;
      dly[v] = 0;
      mis_s[v] = 0;
      row_ptr_s[v] = row_ptr_g[v];
      col_ptr_s[v] = col_ptr_g[v];
      unc[0][v] = v;
    }
    if (t == 0) {
      row_ptr_s[NN] = row_ptr_g[NN];
      col_ptr_s[NN] = col_ptr_g[NN];
      ucnt[0] = NN;
      ucnt[1] = 0;
      dcnt = 0;
      cnt = 0;
    }
    __syncthreads();

    int cur = 0;
    for (int round = 0; round < NN; ++round) {
      int U = ucnt[cur];
      if (round) {  // R0: batched reset
        for (int v = t; v < NN; v += 1024) {
          mr[v] = cov[v] ? SEN : rank_s[v];
          dly[v] = 0;
        }
        if (t == 0) { ucnt[cur ^ 1] = 0; dcnt = 0; }
        __syncthreads();
      }
      // A: min hop0 scatter from uncovered sources
      for (int i = t; i < U; i += 1024) {
        int v = unc[cur][i];
        int val = rank_s[v];
        int e0 = row_ptr_s[v];
        int nch = (row_ptr_s[v + 1] - e0) >> 3;
        const uint4* b4 = col4 + (e0 >> 3);
        for (int cI = 0; cI < nch; cI += 2) {
          uint4 A = b4[cI], B = b4[cI + 1];
          atomicMin(&mr[A.x & 0xFFFFu], val); atomicMin(&mr[A.x >> 16], val);
          atomicMin(&mr[A.y & 0xFFFFu], val); atomicMin(&mr[A.y >> 16], val);
          atomicMin(&mr[A.z & 0xFFFFu], val); atomicMin(&mr[A.z >> 16], val);
          atomicMin(&mr[A.w & 0xFFFFu], val); atomicMin(&mr[A.w >> 16], val);
          atomicMin(&mr[B.x & 0xFFFFu], val); atomicMin(&mr[B.x >> 16], val);
          atomicMin(&mr[B.y & 0xFFFFu], val); atomicMin(&mr[B.y >> 16], val);
          atomicMin(&mr[B.z & 0xFFFFu], val); atomicMin(&mr[B.z >> 16], val);
          atomicMin(&mr[B.w & 0xFFFFu], val); atomicMin(&mr[B.w >> 16], val);
        }
      }
      __syncthreads();
      // CD: min hop1 gather (CSC) + delta detect + dl append
      for (int i = t; i < U; i += 1024) {
        int v = unc[cur][i];
        int val = mr[v];
        int e0 = col_ptr_s[v];
        int nch = (col_ptr_s[v + 1] - e0) >> 3;
        const uint4* b4 = row4 + (e0 >> 3);
        for (int cI = 0; cI < nch; cI += 2) {
          uint4 A = b4[cI], B = b4[cI + 1];
          int m0 = min(mr[A.x & 0xFFFFu], mr[A.x >> 16]);
          int m1 = min(mr[A.y & 0xFFFFu], mr[A.y >> 16]);
          int m2 = min(mr[A.z & 0xFFFFu], mr[A.z >> 16]);
          int m3 = min(mr[A.w & 0xFFFFu], mr[A.w >> 16]);
          int m4 = min(mr[B.x & 0xFFFFu], mr[B.x >> 16]);
          int m5 = min(mr[B.y & 0xFFFFu], mr[B.y >> 16]);
          int m6 = min(mr[B.z & 0xFFFFu], mr[B.z >> 16]);
          int m7 = min(mr[B.w & 0xFFFFu], mr[B.w >> 16]);
          val = min(val, min(min(min(m0, m1), min(m2, m3)),
                             min(min(m4, m5), min(m6, m7))));
        }
        if (rank_s[v] == val) {
          mis_s[v] = 1;
          dly[v] = 1;  // keep-self of OR hop0
          dl[atomicAdd(&dcnt, 1)] = v;  // unordered (consumers order-free)
        }
      }
      __syncthreads();
      // E: OR hop0 scatter from delta
      int D = dcnt;
      for (int i = t; i < D; i += 1024) {
        int v = dl[i];
        int e0 = row_ptr_s[v];
        int nch = (row_ptr_s[v + 1] - e0) >> 3;
        const uint4* b4 = col4 + (e0 >> 3);
        for (int cI = 0; cI < nch; cI += 2) {
          uint4 A = b4[cI], B = b4[cI + 1];
          dly[A.x & 0xFFFFu] = 1; dly[A.x >> 16] = 1;
          dly[A.y & 0xFFFFu] = 1; dly[A.y >> 16] = 1;
          dly[A.z & 0xFFFFu] = 1; dly[A.z >> 16] = 1;
          dly[A.w & 0xFFFFu] = 1; dly[A.w >> 16] = 1;
          dly[B.x & 0xFFFFu] = 1; dly[B.x >> 16] = 1;
          dly[B.y & 0xFFFFu] = 1; dly[B.y >> 16] = 1;
          dly[B.z & 0xFFFFu] = 1; dly[B.z >> 16] = 1;
          dly[B.w & 0xFFFFu] = 1; dly[B.w >> 16] = 1;
        }
      }
      __syncthreads();
      // GH: OR hop1 gather (CSC) + fold + survivor-list rebuild
      for (int i = t; i < U; i += 1024) {
        int v = unc[cur][i];
        int c1 = dly[v];
        if (!c1) {
          int e0 = col_ptr_s[v];
          int nch = (col_ptr_s[v + 1] - e0) >> 3;
          const uint4* b4 = row4 + (e0 >> 3);
          for (int cI = 0; cI < nch; cI += 2) {
            uint4 A = b4[cI], B = b4[cI + 1];
            c1 |= dly[A.x & 0xFFFFu] | dly[A.x >> 16] |
                  dly[A.y & 0xFFFFu] | dly[A.y >> 16] |
                  dly[A.z & 0xFFFFu] | dly[A.z >> 16] |
                  dly[A.w & 0xFFFFu] | dly[A.w >> 16] |
                  dly[B.x & 0xFFFFu] | dly[B.x >> 16] |
                  dly[B.y & 0xFFFFu] | dly[B.y >> 16] |
                  dly[B.z & 0xFFFFu] | dly[B.z >> 16] |
                  dly[B.w & 0xFFFFu] | dly[B.w >> 16];
            if (c1) break;
          }
        }
        if (c1) cov[v] = 1;
        else unc[cur ^ 1][atomicAdd(&ucnt[cur ^ 1], 1)] = v;
      }
      __syncthreads();
      if (ucnt[cur ^ 1] == 0) break;
      cur ^= 1;
    }

    for (int v = t; v < NN; v += 1024) {
      int s = mis_s[v];
      mis_flag[v] = s;
      if (s) mis_list[atomicAdd(&cnt, 1)] = v;
    }
    __syncthreads();
    if (t == 0) *mis_count = cnt;
  } else {
    // ---------------- rw row build + output-zero role (verbatim) ----------
    __shared__ float rowbuf[NN];
    __shared__ float ssum;
    int i = blockIdx.x - 1;
    int t = threadIdx.x;
    // zero adj_c slice (8KB/block) and x_pool slice (2KB/block) in the shadow
    float4 z4 = make_float4(0.f, 0.f, 0.f, 0.f);
    if (t < 512) ((float4*)(adjc + (size_t)i * NN))[t] = z4;
    if (t < 128) ((float4*)xp)[(size_t)i * 128 + t] = z4;
    for (int j = t; j < NN; j += 1024) rowbuf[j] = 0.f;
    if (t == 0) ssum = 0.f;
    __syncthreads();
    int e0 = row_ptr_g[i], e1 = row_ptr_g[i + 1];
    float part = 0.f;
    for (int e = e0 + t; e < e1; e += 1024) {  // deg < 256 => same edge->thread map
      float a = avals[e];
      atomicAdd(&rowbuf[colidx[e]], a);
      part += a;
    }
    for (int off = 32; off; off >>= 1) part += __shfl_down(part, off);
    if ((t & 63) == 0) atomicAdd(&ssum, part);
    __syncthreads();
    float s = ssum;
    s = (s > 0.f) ? s : 1.f;
    for (int j = t; j < NN; j += 1024) {
      float v = rowbuf[j] / s;
      v = (i == j) ? (v + EPSV) : (v * (1.f - EPSV));
      rw[(size_t)i * NN + j] = v;
    }
  }
}

// ---------------------------------------------------------------------------
// Bc compact-row gather from rw columns — ONCE, globally (verified).
// ---------------------------------------------------------------------------
__global__ __launch_bounds__(256) void bc_gather(const float* __restrict__ rw,
                                                 const int* __restrict__ mis_list,
                                                 const int* __restrict__ mis_count,
                                                 float* __restrict__ Bc) {
  int M = *mis_count;
  int total = M * NN;
  int stride = gridDim.x * 256;
  for (int j = blockIdx.x * 256 + threadIdx.x; j < total; j += stride) {
    int tc = j >> 11, i = j & (NN - 1);
    Bc[(size_t)tc * NN + i] = rw[(size_t)i * NN + mis_list[tc]];
  }
}

// ---------------------------------------------------------------------------
// c2 + Gumbel-argmax + DIRECT decode/counts. The j-loop math is the
// R5/R6-verified single pass (warp owns 2 rows, streams all M Bc columns);
// the ending is the R4-verified direct cluster/counts write (pdecode
// preserved, counts pre-zeroed in csr_scan_pad).
// ---------------------------------------------------------------------------
__device__ inline unsigned int f32_key(float x) {
  unsigned int u = __float_as_uint(x);
  return (u & 0x80000000u) ? ~u : (u | 0x80000000u);
}
__device__ inline float dot4(float4 a, float4 b) {
  return ((a.x * b.x + a.y * b.y) + (a.z * b.z + a.w * b.w));
}
__device__ inline unsigned long long umax64(unsigned long long a, unsigned long long b) {
  return a > b ? a : b;
}
__device__ inline int pdecode(unsigned long long p) {
  return (p == 0ull) ? 0 : (NN - 1 - (int)(p & 0xFFFFFFFFull));
}

__global__ __launch_bounds__(256) void c2_all(const float* __restrict__ rw,
                                              const float* __restrict__ Bc,
                                              const float* __restrict__ u,
                                              const int* __restrict__ mis_list,
                                              const int* __restrict__ mis_count,
                                              int* __restrict__ cluster,
                                              int* __restrict__ counts) {
  int M = *mis_count;
  int lane = threadIdx.x & 63, w = threadIdx.x >> 6;
  int r0 = blockIdx.x * 8 + w * 2;  // 256 blocks x 4 warps x 2 rows = 2048
  const float4* rp0 = (const float4*)(rw + (size_t)r0 * NN);
  const float4* rp1 = (const float4*)(rw + (size_t)(r0 + 1) * NN);
  float4 A0[8], A1[8];
#pragma unroll
  for (int q = 0; q < 8; ++q) {
    A0[q] = rp0[q * 64 + lane];
    A1[q] = rp1[q * 64 + lane];
  }
  unsigned long long best0 = 0ull, best1 = 0ull;
  for (int j = 0; j < M; ++j) {
    int m = mis_list[j];
    const float4* cb = (const float4*)(Bc + (size_t)j * NN);
    float4 B[8];
#pragma unroll
    for (int q = 0; q < 8; ++q) B[q] = cb[q * 64 + lane];
    // row 0 — identical tree + shuffle order as the verified kernel
    float s01 = dot4(A0[0], B[0]) + dot4(A0[1], B[1]);
    float s23 = dot4(A0[2], B[2]) + dot4(A0[3], B[3]);
    float s45 = dot4(A0[4], B[4]) + dot4(A0[5], B[5]);
    float s67 = dot4(A0[6], B[6]) + dot4(A0[7], B[7]);
    float s = (s01 + s23) + (s45 + s67);
    s += __shfl_xor(s, 32);
    s += __shfl_xor(s, 16);
    s += __shfl_xor(s, 8);
    s += __shfl_xor(s, 4);
    s += __shfl_xor(s, 2);
    s += __shfl_xor(s, 1);
    // row 1
    float t01 = dot4(A1[0], B[0]) + dot4(A1[1], B[1]);
    float t23 = dot4(A1[2], B[2]) + dot4(A1[3], B[3]);
    float t45 = dot4(A1[4], B[4]) + dot4(A1[5], B[5]);
    float t67 = dot4(A1[6], B[6]) + dot4(A1[7], B[7]);
    float tt = (t01 + t23) + (t45 + t67);
    tt += __shfl_xor(tt, 32);
    tt += __shfl_xor(tt, 16);
    tt += __shfl_xor(tt, 8);
    tt += __shfl_xor(tt, 4);
    tt += __shfl_xor(tt, 2);
    tt += __shfl_xor(tt, 1);
    if (lane == 0) {
      if (s > 0.f) {
        float uu = u[(size_t)r0 * NN + m];
        float g = -logf(-logf(uu + 1e-20f) + 1e-20f);
        float logit = logf(s) + g;
        best0 = umax64(best0, ((unsigned long long)f32_key(logit) << 32) |
                                  (unsigned int)(NN - 1 - m));
      }
      if (tt > 0.f) {
        float uu = u[(size_t)(r0 + 1) * NN + m];
        float g = -logf(-logf(uu + 1e-20f) + 1e-20f);
        float logit = logf(tt) + g;
        best1 = umax64(best1, ((unsigned long long)f32_key(logit) << 32) |
                                  (unsigned int)(NN - 1 - m));
      }
    }
  }
  if (lane == 0) {
    int m0b = pdecode(best0);
    cluster[r0] = m0b;
    atomicAdd(&counts[m0b], 1);
    int m1b = pdecode(best1);
    cluster[r0 + 1] = m1b;
    atomicAdd(&counts[m1b], 1);
  }
}

// ---------------------------------------------------------------------------
// Final fused pass (verified, R8 verbatim): c_hard + p_inv + mis writes,
// adj_c edge scatter, PRE-SCALED x_pool accumulation via atomics (the R11
// ownership-gather alternative was 4x slower: serial per-block loops).
// ---------------------------------------------------------------------------
__global__ __launch_bounds__(256) void scatter_chpm(const int* __restrict__ row,
                                                    const int* __restrict__ col,
                                                    const float* __restrict__ attr,
                                                    const float* __restrict__ x,
                                                    const int* __restrict__ cluster,
                                                    const int* __restrict__ counts,
                                                    const int* __restrict__ mis_flag,
                                                    float* __restrict__ out_ch,
                                                    float* __restrict__ out_pinv,
                                                    float* __restrict__ out_mis,
                                                    float* __restrict__ adjc,
                                                    float* __restrict__ xp) {
  int idx = blockIdx.x * 256 + threadIdx.x;  // over N*N
  int a = idx >> 11, b = idx & (NN - 1);
  out_ch[idx] = (cluster[a] == b) ? 1.f : 0.f;
  float pv = 0.f;
  if (cluster[b] == a) {
    int c = counts[a];
    pv = 1.f / (float)(c > 0 ? c : 1);
  }
  out_pinv[idx] = pv;
  if (idx < NN) out_mis[idx] = mis_flag[idx] ? 1.f : 0.f;
  if (idx < NN * DD) {
    int i = idx >> 9;
    int ci = cluster[i];
    int c = counts[ci];
    atomicAdd(&xp[ci * DD + (idx & (DD - 1))], x[idx] / (float)(c > 0 ? c : 1));
  }
  if (idx < EE) {
    atomicAdd(&adjc[(size_t)cluster[row[idx]] * NN + cluster[col[idx]]], attr[idx]);
  }
}

// ---------------------------------------------------------------------------
extern "C" void kernel_launch(void* const* d_in, const int* in_sizes, int n_in,
                              void* d_out, int out_size, void* d_ws, size_t ws_size,
                              hipStream_t stream) {
  const int*   edge_index = (const int*)d_in[0];
  const float* edge_attr  = (const float*)d_in[1];
  const float* x          = (const float*)d_in[2];
  const int*   rank       = (const int*)d_in[3];
  const float* u          = (const float*)d_in[4];
  float* out              = (float*)d_out;  // f32 outputs, concatenated

  const int* row = edge_index;
  const int* col = edge_index + EE;

  float* out_adjc = out;                 // N*N — zeroed early (fused), adj_c scatter target
  float* out_ch   = out + SZ;            // N*N — doubles as Bc scratch
  float* out_pinv = out + 2 * SZ;        // N*N — doubles as rw scratch
  float* out_mis  = out + 3 * SZ;        // N
  float* out_xp   = out + 3 * SZ + NN;   // N*D

  // d_ws layout (~896 KB). NO memset: pdeg/pcdeg fully written by
  // count_deg8; counts zeroed inside csr_scan_pad; everything else fully
  // written before read.
  int*   counts    = (int*)d_ws;                   // N
  int*   mis_flag  = counts + NN;                  // N
  int*   cluster   = mis_flag + NN;                // N
  int*   mis_list  = cluster + NN;                 // N
  int*   mis_count = mis_list + NN;                // 1
  int*   fill_ptr  = mis_count + 1;                // N
  int*   cfill_ptr = fill_ptr + NN;                // N
  int*   row_ptr   = cfill_ptr + NN;               // N+1
  int*   col_ptr   = row_ptr + NN + 1;             // N+1
  int*   pdeg      = col_ptr + NN + 1;             // NPART*N partial histograms
  int*   pcdeg     = pdeg + NPART * NN;            // NPART*N
  unsigned short* colidx =                          // PADE u16, 32B-aligned
      (unsigned short*)(((uintptr_t)(pcdeg + NPART * NN) + 31) & ~(uintptr_t)31);
  unsigned short* rowidx = colidx + PADE;          // PADE u16
  float* avals = (float*)(rowidx + PADE);          // PADE f32 (CSR edge weights)

  count_deg8<<<NPART, 1024, 0, stream>>>(row, col, pdeg, pcdeg);
  csr_scan_pad<<<1, 1024, 0, stream>>>(pdeg, pcdeg, row_ptr, fill_ptr, col_ptr,
                                       cfill_ptr, colidx, rowidx, avals, counts);
  csr_fill<<<EE / 256, 256, 0, stream>>>(row, col, edge_attr, fill_ptr, cfill_ptr,
                                         colidx, rowidx, avals);
  // block 0 = MIS (1 CU, ~47us); blocks 1..NN = rw rows + adjc/xp zeroing (hidden)
  fused_mis_rw<<<NN + 1, 1024, 0, stream>>>(row_ptr, col_ptr, colidx, rowidx, rank,
                                            mis_flag, mis_list, mis_count,
                                            avals, out_pinv /*rw*/, out_adjc, out_xp);
  bc_gather<<<256, 256, 0, stream>>>(out_pinv, mis_list, mis_count, out_ch);
  c2_all<<<NN / 8, 256, 0, stream>>>(out_pinv, out_ch, u, mis_list, mis_count,
                                     cluster, counts);
  scatter_chpm<<<(NN * NN) / 256, 256, 0, stream>>>(row, col, edge_attr, x, cluster,
                                                    counts, mis_flag, out_ch, out_pinv,
                                                    out_mis, out_adjc, out_xp);
}